// Round 10
// baseline (502.684 us; speedup 1.0000x reference)
//
#include <hip/hip_runtime.h>
#include <math.h>

// Problem constants
#define B_   8
#define C_   128
#define C2_  256
#define H_   128
#define W_   128
#define HW_  16384
#define CR_  32
#define EPS_ 1e-5f
#define NS_  32     // n-splits for sim partial sums

typedef _Float16 f16;
typedef f16 f16x8 __attribute__((ext_vector_type(8)));
typedef f16 f16x4 __attribute__((ext_vector_type(4)));
typedef float f32x4 __attribute__((ext_vector_type(4)));

// ---------------------------------------------------------------------------
// Kernel 1: prep — avg partials (per-h slices, no atomics) + NHWC f16 repack
//           + fused conv-weight repack (288 elements per block).
// avgp layout [h][b][c] -> fully coalesced writes and reads.
// ---------------------------------------------------------------------------
__global__ __launch_bounds__(256) void prep_kernel(
    const float* __restrict__ x1, const float* __restrict__ x2,
    const float* __restrict__ conv_w,
    float* __restrict__ avgp, f16* __restrict__ xs, f16* __restrict__ wt)
{
    __shared__ f16 T[W_ * 136];
    __shared__ float part[C2_];
    int h = blockIdx.x, b = blockIdx.y;
    int tid = threadIdx.x;
    f16* out = xs + ((size_t)b * H_ + h) * W_ * C2_;
    for (int p = 0; p < 2; ++p) {
        const float* src = p ? x2 : x1;
        __syncthreads();
        for (int idx = tid; idx < C_ * 32; idx += 256) {
            int c = idx >> 5, w4 = (idx & 31) << 2;
            const float4 v = *(const float4*)&src[(((size_t)b * C_ + c) * H_ + h) * W_ + w4];
            float s = v.x + v.y + v.z + v.w;
            s += __shfl_xor(s, 1, 64);  s += __shfl_xor(s, 2, 64);
            s += __shfl_xor(s, 4, 64);  s += __shfl_xor(s, 8, 64);
            s += __shfl_xor(s, 16, 64);
            if ((tid & 31) == 0) part[p * C_ + c] = s;
            int cs = c ^ (8 * ((idx & 31) & 15));
            T[(w4 + 0) * 136 + cs] = (f16)v.x;
            T[(w4 + 1) * 136 + cs] = (f16)v.y;
            T[(w4 + 2) * 136 + cs] = (f16)v.z;
            T[(w4 + 3) * 136 + cs] = (f16)v.w;
        }
        __syncthreads();
        for (int u = tid; u < W_ * 16; u += 256) {
            int w = u >> 4, o = u & 15;
            f16x8 v = *(const f16x8*)&T[w * 136 + ((o * 8) ^ (8 * ((w >> 2) & 15)))];
            *(f16x8*)&out[w * C2_ + p * C_ + o * 8] = v;
        }
    }
    __syncthreads();
    avgp[((size_t)h * B_ + b) * C2_ + tid] = part[tid];
    // fused weight repack: wt[cc][t][co][32ci], 288 elems per block, exact cover
    {
        int base = (b * H_ + h) * 288;
        for (int i = tid; i < 288; i += 256) {
            int idx = base + i;
            int ci = idx & 31;
            int co = (idx >> 5) & 127;
            int tt = idx >> 12;
            int cc = tt / 9, t = tt - cc * 9;
            wt[idx] = (f16)conv_w[((size_t)co * C2_ + cc * 32 + ci) * 9 + t];
        }
    }
}

// ---------------------------------------------------------------------------
// Kernel 2: SE MLP, one block per batch (8 blocks)
// ---------------------------------------------------------------------------
__global__ __launch_bounds__(256) void se_mlp_kernel(
    const float* __restrict__ avgp, const float* __restrict__ w1,
    const float* __restrict__ w2, float* __restrict__ se)
{
    int b = blockIdx.x;
    __shared__ float s_avg[C2_];
    __shared__ float s_h[CR_];
    float s = 0.f;
    for (int h = 0; h < H_; ++h)
        s += avgp[((size_t)h * B_ + b) * C2_ + threadIdx.x];
    s_avg[threadIdx.x] = s * (1.f / (float)HW_);
    __syncthreads();
    {
        int j = threadIdx.x >> 3, sub = threadIdx.x & 7;   // 8 threads per output
        float a = 0.f;
        #pragma unroll 8
        for (int k = sub * 32; k < sub * 32 + 32; ++k) a += s_avg[k] * w1[j * C2_ + k];
        a += __shfl_xor(a, 1, 64); a += __shfl_xor(a, 2, 64); a += __shfl_xor(a, 4, 64);
        if (sub == 0) s_h[j] = fmaxf(a, 0.f);
    }
    __syncthreads();
    float o = 0.f;
    #pragma unroll
    for (int j = 0; j < CR_; ++j) o += s_h[j] * w2[threadIdx.x * CR_ + j];
    se[b * C2_ + threadIdx.x] = 1.f / (1.f + expf(-o));
}

// ---------------------------------------------------------------------------
// Kernel 3: conv implicit GEMM, fp16 MFMA.
// v2: 1024 threads = 16 waves (was 512/8). Wave mapping:
//   half = wave&1 (co half, 64 chans), nh = (wave>>1)&1 (n half), orow = wave>>2.
// acc per wave: 4x4 (64 regs, was 128) -> 4 waves/SIMD resident (was 2),
// doubling latency-hiding for ds_read->MFMA chains and barrier phases.
// Same LDS layouts; reg-preload of chunk cc+1 split over 2x threads.
// ---------------------------------------------------------------------------
#define WS_F16  46080            // 9*128*40
#define XS_F16  24960            // 24*130*8
#define SMEM_BYTES 142592        // (46080+24960+256)*2

__global__ __launch_bounds__(1024, 4) void conv_mfma_big(
    const f16* __restrict__ xs, const f16* __restrict__ wt,
    const float* __restrict__ se,
    const float* __restrict__ bn_gamma, const float* __restrict__ bn_beta,
    const float* __restrict__ bn_mean, const float* __restrict__ bn_var,
    f16* __restrict__ yh, f16* __restrict__ yt)
{
    extern __shared__ __align__(16) f16 smem[];
    f16* Ws  = smem;                       // 46080 f16
    f16* Xs  = smem + WS_F16;              // 24960 f16
    f16* seh = smem + WS_F16 + XS_F16;     // 256 f16

    int h0 = blockIdx.x * 4, b = blockIdx.y;
    int tid = threadIdx.x;
    int wave = tid >> 6, lane = tid & 63;
    int half = wave & 1, nh = (wave >> 1) & 1, orow = wave >> 2;
    int lr = lane & 15, kg = lane >> 4;
    const f16* xsb = xs + (size_t)b * ((size_t)H_ * W_ * C2_);

    if (tid < 256) seh[tid] = (f16)se[b * C2_ + tid];
    __syncthreads();

    f32x4 acc[4][4];
    #pragma unroll
    for (int i = 0; i < 4; ++i)
        #pragma unroll
        for (int j = 0; j < 4; ++j)
            #pragma unroll
            for (int r = 0; r < 4; ++r) acc[i][j][r] = 0.f;

    f16x8 wreg[5], xreg[4];

    auto preload = [&](int cc) {
        const f16* wsrc = wt + (size_t)cc * 36864;
        #pragma unroll
        for (int k = 0; k < 5; ++k) {
            int u = k * 1024 + tid;
            if (u < 4608) wreg[k] = *(const f16x8*)&wsrc[u * 8];
        }
        #pragma unroll
        for (int k = 0; k < 4; ++k) {
            int u = k * 1024 + tid;
            f16x8 v;
            #pragma unroll
            for (int z = 0; z < 8; ++z) v[z] = (f16)0.f;
            if (u < 3120) {
                int r = u / 520, rem = u - r * 520;
                int col = rem >> 2, q = rem & 3;
                int gh = h0 - 1 + r, gw = col - 1;
                if ((unsigned)gh < (unsigned)H_ && (unsigned)gw < (unsigned)W_) {
                    v = *(const f16x8*)&xsb[((size_t)(gh * W_ + gw)) * C2_ + cc * 32 + q * 8];
                    f16x8 sv = *(const f16x8*)&seh[cc * 32 + q * 8];
                    v = v * sv;
                }
            }
            xreg[k] = v;
        }
    };

    preload(0);

    for (int cc = 0; cc < 8; ++cc) {
        __syncthreads();            // consumers of previous chunk done
        // regs -> LDS
        #pragma unroll
        for (int k = 0; k < 5; ++k) {
            int u = k * 1024 + tid;
            if (u < 4608)
                *(f16x8*)&Ws[(u >> 2) * 40 + (u & 3) * 8] = wreg[k];
        }
        #pragma unroll
        for (int k = 0; k < 4; ++k) {
            int u = k * 1024 + tid;
            if (u < 3120) {
                int r = u / 520, rem = u - r * 520;
                int col = rem >> 2, q = rem & 3;
                *(f16x8*)&Xs[((r * 4 + q) * 130 + col) * 8] = xreg[k];
            }
        }
        __syncthreads();
        if (cc < 7) preload(cc + 1);   // global loads in flight during MFMAs
        #pragma unroll
        for (int t = 0; t < 9; ++t) {
            const int dh = t / 3, dw = t % 3;
            const int rr = orow + dh;
            f16x8 bf[4];
            #pragma unroll
            for (int j = 0; j < 4; ++j)
                bf[j] = *(const f16x8*)&Xs[((rr * 4 + kg) * 130 +
                            (nh * 64 + j * 16 + lr + dw)) * 8];
            #pragma unroll
            for (int i2 = 0; i2 < 4; ++i2) {
                f16x8 af = *(const f16x8*)&Ws[(t * 128 + half * 64 + i2 * 16 + lr) * 40 + kg * 8];
                #pragma unroll
                for (int j = 0; j < 4; ++j)
                    acc[i2][j] = __builtin_amdgcn_mfma_f32_16x16x32_f16(
                        af, bf[j], acc[i2][j], 0, 0, 0);
            }
        }
    }
    // epilogue: BN+ReLU; D layout col(lane&15)=n, row=kg*4+r(+16*i2)=c.
    int h = h0 + orow;
    f16x4 tvv[4][4];
    #pragma unroll
    for (int i2 = 0; i2 < 4; ++i2) {
        int cb = half * 64 + i2 * 16 + kg * 4;
        float inv[4], add[4];
        #pragma unroll
        for (int r = 0; r < 4; ++r) {
            int c = cb + r;
            inv[r] = bn_gamma[c] * rsqrtf(bn_var[c] + EPS_);
            add[r] = bn_beta[c] - bn_mean[c] * inv[r];
        }
        #pragma unroll
        for (int j = 0; j < 4; ++j) {
            int n = nh * 64 + j * 16 + lr;
            f16x4 tv;
            #pragma unroll
            for (int r = 0; r < 4; ++r) {
                float v = fmaxf(acc[i2][j][r] * inv[r] + add[r], 0.f);
                tv[r] = (f16)v;
                yh[((size_t)b * C_ + cb + r) * HW_ + h * W_ + n] = (f16)v;
            }
            tvv[i2][j] = tv;
        }
    }
    // yt via 4-pass LDS transpose (reuse Xs region: 128*136 f16 = 17408 <= 24960)
    f16* T = Xs;
    for (int ro = 0; ro < 4; ++ro) {
        __syncthreads();
        if (orow == ro) {
            #pragma unroll
            for (int i2 = 0; i2 < 4; ++i2)
                #pragma unroll
                for (int j = 0; j < 4; ++j)
                    *(f16x4*)&T[(nh * 64 + j * 16 + lr) * 136 + half * 64 + i2 * 16 + kg * 4] = tvv[i2][j];
        }
        __syncthreads();
        for (int u = tid; u < 2048; u += 1024) {
            int n = u >> 4, o8 = u & 15;
            *(f16x8*)&yt[((size_t)b * HW_ + (h0 + ro) * W_ + n) * C_ + o8 * 8] =
                *(const f16x8*)&T[n * 136 + o8 * 8];
        }
    }
}

// ---------------------------------------------------------------------------
// Kernel 4: sim partials via MFMA (unchanged)
// ---------------------------------------------------------------------------
__global__ __launch_bounds__(512) void sim_mfma_kernel(
    const f16* __restrict__ yh, float* __restrict__ simp)
{
    int ns = blockIdx.x, b = blockIdx.y;
    int tid = threadIdx.x, wave = tid >> 6, lane = tid & 63;
    int wm = wave >> 2, wn = wave & 3;
    int lr = lane & 15, kg = lane >> 4;
    const f16* Y = yh + (size_t)b * C_ * HW_;
    int n0 = ns * (HW_ / NS_);

    f32x4 acc[4][2];
    #pragma unroll
    for (int i = 0; i < 4; ++i)
        #pragma unroll
        for (int j = 0; j < 2; ++j)
            #pragma unroll
            for (int r = 0; r < 4; ++r) acc[i][j][r] = 0.f;

    for (int kk = 0; kk < 16; ++kk) {
        int k = n0 + kk * 32 + kg * 8;
        f16x8 af[4], bf[2];
        #pragma unroll
        for (int i = 0; i < 4; ++i)
            af[i] = *(const f16x8*)&Y[(size_t)(wm * 64 + i * 16 + lr) * HW_ + k];
        #pragma unroll
        for (int j = 0; j < 2; ++j)
            bf[j] = *(const f16x8*)&Y[(size_t)(wn * 32 + j * 16 + lr) * HW_ + k];
        #pragma unroll
        for (int i = 0; i < 4; ++i)
            #pragma unroll
            for (int j = 0; j < 2; ++j)
                acc[i][j] = __builtin_amdgcn_mfma_f32_16x16x32_f16(af[i], bf[j], acc[i][j], 0, 0, 0);
    }
    float* dst = simp + (size_t)(ns * B_ + b) * C_ * C_;
    #pragma unroll
    for (int i = 0; i < 4; ++i)
        #pragma unroll
        for (int j = 0; j < 2; ++j)
            #pragma unroll
            for (int r = 0; r < 4; ++r)
                dst[(wm * 64 + i * 16 + kg * 4 + r) * C_ + wn * 32 + j * 16 + lr] = acc[i][j][r];
}

// ---------------------------------------------------------------------------
// Kernel 5: reduce partials + softmax(-sim) -> Ph fp16 (unchanged)
// ---------------------------------------------------------------------------
__global__ __launch_bounds__(128) void softmax_kernel(
    const float* __restrict__ simp, f16* __restrict__ Ph)
{
    int bc = blockIdx.x;
    int b = bc / C_;
    int d = threadIdx.x;
    float s = 0.f;
    for (int ns = 0; ns < NS_; ++ns)
        s += simp[((size_t)(ns * B_ + b) * C_ + (bc % C_)) * C_ + d];
    float v = -s;
    float m = v;
    #pragma unroll
    for (int off = 32; off > 0; off >>= 1) m = fmaxf(m, __shfl_xor(m, off, 64));
    __shared__ float sm[2], ss[2];
    int wid = threadIdx.x >> 6;
    if ((threadIdx.x & 63) == 0) sm[wid] = m;
    __syncthreads();
    m = fmaxf(sm[0], sm[1]);
    float p = expf(v - m);
    float sum = p;
    #pragma unroll
    for (int off = 32; off > 0; off >>= 1) sum += __shfl_xor(sum, off, 64);
    if ((threadIdx.x & 63) == 0) ss[wid] = sum;
    __syncthreads();
    sum = ss[0] + ss[1];
    Ph[(size_t)bc * C_ + d] = (f16)(p / sum);
}

// ---------------------------------------------------------------------------
// Kernel 6: feat = P @ y via MFMA; out = gamma*feat + y (unchanged)
// ---------------------------------------------------------------------------
__global__ __launch_bounds__(256) void feat_mfma_kernel(
    const f16* __restrict__ Ph, const f16* __restrict__ yt,
    const f16* __restrict__ yh,
    const float* __restrict__ gamma, float* __restrict__ out)
{
    int nt = blockIdx.x, b = blockIdx.y;
    int tid = threadIdx.x, wave = tid >> 6, lane = tid & 63;
    int wm = wave >> 1, wn = wave & 1;
    int lr = lane & 15, kg = lane >> 4;
    int n0 = nt * 128;
    const f16* Pb = Ph + (size_t)b * C_ * C_;
    const f16* Yt = yt + (size_t)b * HW_ * C_;

    f32x4 acc[4][4];
    #pragma unroll
    for (int i = 0; i < 4; ++i)
        #pragma unroll
        for (int j = 0; j < 4; ++j)
            #pragma unroll
            for (int r = 0; r < 4; ++r) acc[i][j][r] = 0.f;

    #pragma unroll
    for (int kk = 0; kk < 4; ++kk) {
        int k = kk * 32 + kg * 8;
        f16x8 af[4], bf[4];
        #pragma unroll
        for (int i = 0; i < 4; ++i)
            af[i] = *(const f16x8*)&Pb[(wm * 64 + i * 16 + lr) * C_ + k];
        #pragma unroll
        for (int j = 0; j < 4; ++j)
            bf[j] = *(const f16x8*)&Yt[(size_t)(n0 + wn * 64 + j * 16 + lr) * C_ + k];
        #pragma unroll
        for (int i = 0; i < 4; ++i)
            #pragma unroll
            for (int j = 0; j < 4; ++j)
                acc[i][j] = __builtin_amdgcn_mfma_f32_16x16x32_f16(af[i], bf[j], acc[i][j], 0, 0, 0);
    }
    float g = gamma[0];
    #pragma unroll
    for (int i = 0; i < 4; ++i) {
        int cb = wm * 64 + i * 16 + kg * 4;
        #pragma unroll
        for (int j = 0; j < 4; ++j) {
            int n = n0 + wn * 64 + j * 16 + lr;
            #pragma unroll
            for (int r = 0; r < 4; ++r) {
                float res = (float)yh[((size_t)b * C_ + cb + r) * HW_ + n];
                out[((size_t)b * C_ + cb + r) * HW_ + n] = g * acc[i][j][r] + res;
            }
        }
    }
}

// ---------------------------------------------------------------------------
extern "C" void kernel_launch(void* const* d_in, const int* in_sizes, int n_in,
                              void* d_out, int out_size, void* d_ws, size_t ws_size,
                              hipStream_t stream)
{
    const float* x1       = (const float*)d_in[0];
    const float* x2       = (const float*)d_in[1];
    const float* se_w1    = (const float*)d_in[2];
    const float* se_w2    = (const float*)d_in[3];
    const float* conv_w   = (const float*)d_in[4];
    const float* bn_gamma = (const float*)d_in[5];
    const float* bn_beta  = (const float*)d_in[6];
    const float* bn_mean  = (const float*)d_in[7];
    const float* bn_var   = (const float*)d_in[8];
    const float* gamma    = (const float*)d_in[9];
    float* out = (float*)d_out;

    // Workspace layout — total 135,266,304 B (proven footprint)
    char* ws = (char*)d_ws;
    float* se   = (float*)(ws + 8192);               //    8192 +     8 KB
    f16*   Ph   = (f16*)  (ws + 16384);              //   16384 +   256 KB
    f16*   wt   = (f16*)  (ws + 278528);             //  278528 +   576 KB
    f16*   xs   = (f16*)  (ws + 1048576);            // 1 MB    +    64 MB
    float* simp = (float*)(ws + 1048576);            // aliases xs (post-conv)
    f16*   yh   = (f16*)  (ws + 68157440);           //         +    32 MB
    float* avgp = (float*)(ws + 68157440);           // aliases yh (pre-conv), 1 MB
    f16*   yt   = (f16*)  (ws + 101711872);          //         +    32 MB

    prep_kernel<<<dim3(H_, B_), 256, 0, stream>>>(x1, x2, conv_w, avgp, xs, wt);
    se_mlp_kernel<<<dim3(B_), 256, 0, stream>>>(avgp, se_w1, se_w2, se);

    hipFuncSetAttribute((const void*)conv_mfma_big,
        hipFuncAttributeMaxDynamicSharedMemorySize, SMEM_BYTES);
    conv_mfma_big<<<dim3(H_ / 4, B_), 1024, SMEM_BYTES, stream>>>(
        xs, wt, se, bn_gamma, bn_beta, bn_mean, bn_var, yh, yt);

    sim_mfma_kernel<<<dim3(NS_, B_), 512, 0, stream>>>(yh, simp);
    softmax_kernel<<<dim3(B_ * C_), 128, 0, stream>>>(simp, Ph);
    feat_mfma_kernel<<<dim3(HW_ / 128, B_), 256, 0, stream>>>(Ph, yt, yh, gamma, out);
}

// Round 12
// 386.503 us; speedup vs baseline: 1.3006x; 1.3006x over previous
//
#include <hip/hip_runtime.h>
#include <math.h>

// Problem constants
#define B_   8
#define C_   128
#define C2_  256
#define H_   128
#define W_   128
#define HW_  16384
#define CR_  32
#define EPS_ 1e-5f
#define NS_  32     // n-splits for sim partial sums

typedef _Float16 f16;
typedef f16 f16x8 __attribute__((ext_vector_type(8)));
typedef f16 f16x4 __attribute__((ext_vector_type(4)));
typedef float f32x4 __attribute__((ext_vector_type(4)));

// ---------------------------------------------------------------------------
// Kernel 1: prep — avg partials (per-h slices, no atomics) + NHWC f16 repack
//           + fused conv-weight repack (288 elements per block).
// ---------------------------------------------------------------------------
__global__ __launch_bounds__(256) void prep_kernel(
    const float* __restrict__ x1, const float* __restrict__ x2,
    const float* __restrict__ conv_w,
    float* __restrict__ avgp, f16* __restrict__ xs, f16* __restrict__ wt)
{
    __shared__ f16 T[W_ * 136];
    __shared__ float part[C2_];
    int h = blockIdx.x, b = blockIdx.y;
    int tid = threadIdx.x;
    f16* out = xs + ((size_t)b * H_ + h) * W_ * C2_;
    for (int p = 0; p < 2; ++p) {
        const float* src = p ? x2 : x1;
        __syncthreads();
        for (int idx = tid; idx < C_ * 32; idx += 256) {
            int c = idx >> 5, w4 = (idx & 31) << 2;
            const float4 v = *(const float4*)&src[(((size_t)b * C_ + c) * H_ + h) * W_ + w4];
            float s = v.x + v.y + v.z + v.w;
            s += __shfl_xor(s, 1, 64);  s += __shfl_xor(s, 2, 64);
            s += __shfl_xor(s, 4, 64);  s += __shfl_xor(s, 8, 64);
            s += __shfl_xor(s, 16, 64);
            if ((tid & 31) == 0) part[p * C_ + c] = s;
            int cs = c ^ (8 * ((idx & 31) & 15));
            T[(w4 + 0) * 136 + cs] = (f16)v.x;
            T[(w4 + 1) * 136 + cs] = (f16)v.y;
            T[(w4 + 2) * 136 + cs] = (f16)v.z;
            T[(w4 + 3) * 136 + cs] = (f16)v.w;
        }
        __syncthreads();
        for (int u = tid; u < W_ * 16; u += 256) {
            int w = u >> 4, o = u & 15;
            f16x8 v = *(const f16x8*)&T[w * 136 + ((o * 8) ^ (8 * ((w >> 2) & 15)))];
            *(f16x8*)&out[w * C2_ + p * C_ + o * 8] = v;
        }
    }
    __syncthreads();
    avgp[((size_t)h * B_ + b) * C2_ + tid] = part[tid];
    // fused weight repack: wt[cc][t][co][32ci], 288 elems per block, exact cover
    {
        int base = (b * H_ + h) * 288;
        for (int i = tid; i < 288; i += 256) {
            int idx = base + i;
            int ci = idx & 31;
            int co = (idx >> 5) & 127;
            int tt = idx >> 12;
            int cc = tt / 9, t = tt - cc * 9;
            wt[idx] = (f16)conv_w[((size_t)co * C2_ + cc * 32 + ci) * 9 + t];
        }
    }
}

// ---------------------------------------------------------------------------
// Kernel 2: SE MLP, one block per batch (8 blocks)
// ---------------------------------------------------------------------------
__global__ __launch_bounds__(256) void se_mlp_kernel(
    const float* __restrict__ avgp, const float* __restrict__ w1,
    const float* __restrict__ w2, float* __restrict__ se)
{
    int b = blockIdx.x;
    __shared__ float s_avg[C2_];
    __shared__ float s_h[CR_];
    float s = 0.f;
    for (int h = 0; h < H_; ++h)
        s += avgp[((size_t)h * B_ + b) * C2_ + threadIdx.x];
    s_avg[threadIdx.x] = s * (1.f / (float)HW_);
    __syncthreads();
    {
        int j = threadIdx.x >> 3, sub = threadIdx.x & 7;   // 8 threads per output
        float a = 0.f;
        #pragma unroll 8
        for (int k = sub * 32; k < sub * 32 + 32; ++k) a += s_avg[k] * w1[j * C2_ + k];
        a += __shfl_xor(a, 1, 64); a += __shfl_xor(a, 2, 64); a += __shfl_xor(a, 4, 64);
        if (sub == 0) s_h[j] = fmaxf(a, 0.f);
    }
    __syncthreads();
    float o = 0.f;
    #pragma unroll
    for (int j = 0; j < CR_; ++j) o += s_h[j] * w2[threadIdx.x * CR_ + j];
    se[b * C2_ + threadIdx.x] = 1.f / (1.f + expf(-o));
}

// ---------------------------------------------------------------------------
// Kernel 3: conv implicit GEMM, fp16 MFMA.
// v3: 512 thr / 8 waves, HALF tile (2 h-rows x 64 co) -> LDS 78 KB ->
//     2 blocks/CU = 16 waves/CU = 4 waves/SIMD (v2's occupancy win) while
//     per-thread regs ~105 <= the 128 unified cap (v2 spilled at ~140:
//     FETCH 352MB/WRITE 614MB scratch traffic, MfmaUtil 14%).
// Wave mapping: chalf = wave&1 (32 co), nh = (wave>>1)&1 (64 n), orow = wave>>2.
// acc per wave: 2x4 (32 regs). Grid (H/2, 2, B) = 1024 blocks.
// ---------------------------------------------------------------------------
#define WS_F16  23040            // 9*64*40
#define XS_F16  16640            // 16*130*8
#define SMEM_BYTES 79872         // (23040+16640+256)*2

__global__ __launch_bounds__(512, 4) void conv_mfma_big(
    const f16* __restrict__ xs, const f16* __restrict__ wt,
    const float* __restrict__ se,
    const float* __restrict__ bn_gamma, const float* __restrict__ bn_beta,
    const float* __restrict__ bn_mean, const float* __restrict__ bn_var,
    f16* __restrict__ yh, f16* __restrict__ yt)
{
    extern __shared__ __align__(16) f16 smem[];
    f16* Ws  = smem;                       // 23040 f16
    f16* Xs  = smem + WS_F16;              // 16640 f16
    f16* seh = smem + WS_F16 + XS_F16;     // 256 f16

    int h0 = blockIdx.x * 2, cy = blockIdx.y, b = blockIdx.z;
    int tid = threadIdx.x;
    int wave = tid >> 6, lane = tid & 63;
    int chalf = wave & 1, nh = (wave >> 1) & 1, orow = wave >> 2;
    int lr = lane & 15, kg = lane >> 4;
    const f16* xsb = xs + (size_t)b * ((size_t)H_ * W_ * C2_);

    if (tid < 256) seh[tid] = (f16)se[b * C2_ + tid];
    __syncthreads();

    f32x4 acc[2][4];
    #pragma unroll
    for (int i = 0; i < 2; ++i)
        #pragma unroll
        for (int j = 0; j < 4; ++j)
            #pragma unroll
            for (int r = 0; r < 4; ++r) acc[i][j][r] = 0.f;

    f16x8 wreg[5], xreg[5];

    auto preload = [&](int cc) {
        const f16* wsrc = wt + (size_t)cc * 36864;
        // W: this block's 64-co slice of chunk cc -> 2304 f16x8 slots
        #pragma unroll
        for (int k = 0; k < 5; ++k) {
            int u = k * 512 + tid;
            if (u < 2304) {
                int row = u >> 2;                     // t*64 + co_local
                wreg[k] = *(const f16x8*)&wsrc[
                    (((row >> 6) * 128 + cy * 64 + (row & 63)) << 5) + ((u & 3) << 3)];
            }
        }
        // X: 4 staged rows (h0-1 .. h0+2) x 130 cols x 4 q -> 2080 slots
        #pragma unroll
        for (int k = 0; k < 5; ++k) {
            int u = k * 512 + tid;
            f16x8 v;
            #pragma unroll
            for (int z = 0; z < 8; ++z) v[z] = (f16)0.f;
            if (u < 2080) {
                int r = u / 520, rem = u - r * 520;
                int col = rem >> 2, q = rem & 3;
                int gh = h0 - 1 + r, gw = col - 1;
                if ((unsigned)gh < (unsigned)H_ && (unsigned)gw < (unsigned)W_) {
                    v = *(const f16x8*)&xsb[((size_t)(gh * W_ + gw)) * C2_ + cc * 32 + q * 8];
                    f16x8 sv = *(const f16x8*)&seh[cc * 32 + q * 8];
                    v = v * sv;
                }
            }
            xreg[k] = v;
        }
    };

    preload(0);

    for (int cc = 0; cc < 8; ++cc) {
        __syncthreads();            // consumers of previous chunk done
        // regs -> LDS
        #pragma unroll
        for (int k = 0; k < 5; ++k) {
            int u = k * 512 + tid;
            if (u < 2304)
                *(f16x8*)&Ws[(u >> 2) * 40 + (u & 3) * 8] = wreg[k];
        }
        #pragma unroll
        for (int k = 0; k < 5; ++k) {
            int u = k * 512 + tid;
            if (u < 2080) {
                int r = u / 520, rem = u - r * 520;
                int col = rem >> 2, q = rem & 3;
                *(f16x8*)&Xs[((r * 4 + q) * 130 + col) * 8] = xreg[k];
            }
        }
        __syncthreads();
        if (cc < 7) preload(cc + 1);   // global loads in flight during MFMAs
        #pragma unroll
        for (int t = 0; t < 9; ++t) {
            const int dh = t / 3, dw = t % 3;
            const int rr = orow + dh;
            f16x8 bf[4];
            #pragma unroll
            for (int j = 0; j < 4; ++j)
                bf[j] = *(const f16x8*)&Xs[((rr * 4 + kg) * 130 +
                            (nh * 64 + j * 16 + lr + dw)) * 8];
            #pragma unroll
            for (int i2 = 0; i2 < 2; ++i2) {
                f16x8 af = *(const f16x8*)&Ws[(t * 64 + chalf * 32 + i2 * 16 + lr) * 40 + kg * 8];
                #pragma unroll
                for (int j = 0; j < 4; ++j)
                    acc[i2][j] = __builtin_amdgcn_mfma_f32_16x16x32_f16(
                        af, bf[j], acc[i2][j], 0, 0, 0);
            }
        }
    }
    // epilogue: BN+ReLU; D layout col(lane&15)=n, row=kg*4+r(+16*i2)=c.
    int h = h0 + orow;
    f16x4 tvv[2][4];
    #pragma unroll
    for (int i2 = 0; i2 < 2; ++i2) {
        int cb = cy * 64 + chalf * 32 + i2 * 16 + kg * 4;
        float inv[4], add[4];
        #pragma unroll
        for (int r = 0; r < 4; ++r) {
            int c = cb + r;
            inv[r] = bn_gamma[c] * rsqrtf(bn_var[c] + EPS_);
            add[r] = bn_beta[c] - bn_mean[c] * inv[r];
        }
        #pragma unroll
        for (int j = 0; j < 4; ++j) {
            int n = nh * 64 + j * 16 + lr;
            f16x4 tv;
            #pragma unroll
            for (int r = 0; r < 4; ++r) {
                float v = fmaxf(acc[i2][j][r] * inv[r] + add[r], 0.f);
                tv[r] = (f16)v;
                yh[((size_t)b * C_ + cb + r) * HW_ + h * W_ + n] = (f16)v;
            }
            tvv[i2][j] = tv;
        }
    }
    // yt via 2-pass LDS transpose (reuse Xs region: 128*72 f16 = 9216 <= 16640)
    f16* T = Xs;
    for (int ro = 0; ro < 2; ++ro) {
        __syncthreads();
        if (orow == ro) {
            #pragma unroll
            for (int i2 = 0; i2 < 2; ++i2)
                #pragma unroll
                for (int j = 0; j < 4; ++j)
                    *(f16x4*)&T[(nh * 64 + j * 16 + lr) * 72 + chalf * 32 + i2 * 16 + kg * 4] = tvv[i2][j];
        }
        __syncthreads();
        for (int u = tid; u < 1024; u += 512) {
            int n = u >> 3, o8 = u & 7;
            *(f16x8*)&yt[((size_t)b * HW_ + (h0 + ro) * W_ + n) * C_ + cy * 64 + o8 * 8] =
                *(const f16x8*)&T[n * 72 + o8 * 8];
        }
    }
}

// ---------------------------------------------------------------------------
// Kernel 4: sim partials via MFMA (unchanged)
// ---------------------------------------------------------------------------
__global__ __launch_bounds__(512) void sim_mfma_kernel(
    const f16* __restrict__ yh, float* __restrict__ simp)
{
    int ns = blockIdx.x, b = blockIdx.y;
    int tid = threadIdx.x, wave = tid >> 6, lane = tid & 63;
    int wm = wave >> 2, wn = wave & 3;
    int lr = lane & 15, kg = lane >> 4;
    const f16* Y = yh + (size_t)b * C_ * HW_;
    int n0 = ns * (HW_ / NS_);

    f32x4 acc[4][2];
    #pragma unroll
    for (int i = 0; i < 4; ++i)
        #pragma unroll
        for (int j = 0; j < 2; ++j)
            #pragma unroll
            for (int r = 0; r < 4; ++r) acc[i][j][r] = 0.f;

    for (int kk = 0; kk < 16; ++kk) {
        int k = n0 + kk * 32 + kg * 8;
        f16x8 af[4], bf[2];
        #pragma unroll
        for (int i = 0; i < 4; ++i)
            af[i] = *(const f16x8*)&Y[(size_t)(wm * 64 + i * 16 + lr) * HW_ + k];
        #pragma unroll
        for (int j = 0; j < 2; ++j)
            bf[j] = *(const f16x8*)&Y[(size_t)(wn * 32 + j * 16 + lr) * HW_ + k];
        #pragma unroll
        for (int i = 0; i < 4; ++i)
            #pragma unroll
            for (int j = 0; j < 2; ++j)
                acc[i][j] = __builtin_amdgcn_mfma_f32_16x16x32_f16(af[i], bf[j], acc[i][j], 0, 0, 0);
    }
    float* dst = simp + (size_t)(ns * B_ + b) * C_ * C_;
    #pragma unroll
    for (int i = 0; i < 4; ++i)
        #pragma unroll
        for (int j = 0; j < 2; ++j)
            #pragma unroll
            for (int r = 0; r < 4; ++r)
                dst[(wm * 64 + i * 16 + kg * 4 + r) * C_ + wn * 32 + j * 16 + lr] = acc[i][j][r];
}

// ---------------------------------------------------------------------------
// Kernel 5: reduce partials + softmax(-sim) -> Ph fp16 (unchanged)
// ---------------------------------------------------------------------------
__global__ __launch_bounds__(128) void softmax_kernel(
    const float* __restrict__ simp, f16* __restrict__ Ph)
{
    int bc = blockIdx.x;
    int b = bc / C_;
    int d = threadIdx.x;
    float s = 0.f;
    for (int ns = 0; ns < NS_; ++ns)
        s += simp[((size_t)(ns * B_ + b) * C_ + (bc % C_)) * C_ + d];
    float v = -s;
    float m = v;
    #pragma unroll
    for (int off = 32; off > 0; off >>= 1) m = fmaxf(m, __shfl_xor(m, off, 64));
    __shared__ float sm[2], ss[2];
    int wid = threadIdx.x >> 6;
    if ((threadIdx.x & 63) == 0) sm[wid] = m;
    __syncthreads();
    m = fmaxf(sm[0], sm[1]);
    float p = expf(v - m);
    float sum = p;
    #pragma unroll
    for (int off = 32; off > 0; off >>= 1) sum += __shfl_xor(sum, off, 64);
    if ((threadIdx.x & 63) == 0) ss[wid] = sum;
    __syncthreads();
    sum = ss[0] + ss[1];
    Ph[(size_t)bc * C_ + d] = (f16)(p / sum);
}

// ---------------------------------------------------------------------------
// Kernel 6: feat = P @ y via MFMA; out = gamma*feat + y (unchanged)
// ---------------------------------------------------------------------------
__global__ __launch_bounds__(256) void feat_mfma_kernel(
    const f16* __restrict__ Ph, const f16* __restrict__ yt,
    const f16* __restrict__ yh,
    const float* __restrict__ gamma, float* __restrict__ out)
{
    int nt = blockIdx.x, b = blockIdx.y;
    int tid = threadIdx.x, wave = tid >> 6, lane = tid & 63;
    int wm = wave >> 1, wn = wave & 1;
    int lr = lane & 15, kg = lane >> 4;
    int n0 = nt * 128;
    const f16* Pb = Ph + (size_t)b * C_ * C_;
    const f16* Yt = yt + (size_t)b * HW_ * C_;

    f32x4 acc[4][4];
    #pragma unroll
    for (int i = 0; i < 4; ++i)
        #pragma unroll
        for (int j = 0; j < 4; ++j)
            #pragma unroll
            for (int r = 0; r < 4; ++r) acc[i][j][r] = 0.f;

    #pragma unroll
    for (int kk = 0; kk < 4; ++kk) {
        int k = kk * 32 + kg * 8;
        f16x8 af[4], bf[4];
        #pragma unroll
        for (int i = 0; i < 4; ++i)
            af[i] = *(const f16x8*)&Pb[(wm * 64 + i * 16 + lr) * C_ + k];
        #pragma unroll
        for (int j = 0; j < 4; ++j)
            bf[j] = *(const f16x8*)&Yt[(size_t)(n0 + wn * 64 + j * 16 + lr) * C_ + k];
        #pragma unroll
        for (int i = 0; i < 4; ++i)
            #pragma unroll
            for (int j = 0; j < 4; ++j)
                acc[i][j] = __builtin_amdgcn_mfma_f32_16x16x32_f16(af[i], bf[j], acc[i][j], 0, 0, 0);
    }
    float g = gamma[0];
    #pragma unroll
    for (int i = 0; i < 4; ++i) {
        int cb = wm * 64 + i * 16 + kg * 4;
        #pragma unroll
        for (int j = 0; j < 4; ++j) {
            int n = n0 + wn * 64 + j * 16 + lr;
            #pragma unroll
            for (int r = 0; r < 4; ++r) {
                float res = (float)yh[((size_t)b * C_ + cb + r) * HW_ + n];
                out[((size_t)b * C_ + cb + r) * HW_ + n] = g * acc[i][j][r] + res;
            }
        }
    }
}

// ---------------------------------------------------------------------------
extern "C" void kernel_launch(void* const* d_in, const int* in_sizes, int n_in,
                              void* d_out, int out_size, void* d_ws, size_t ws_size,
                              hipStream_t stream)
{
    const float* x1       = (const float*)d_in[0];
    const float* x2       = (const float*)d_in[1];
    const float* se_w1    = (const float*)d_in[2];
    const float* se_w2    = (const float*)d_in[3];
    const float* conv_w   = (const float*)d_in[4];
    const float* bn_gamma = (const float*)d_in[5];
    const float* bn_beta  = (const float*)d_in[6];
    const float* bn_mean  = (const float*)d_in[7];
    const float* bn_var   = (const float*)d_in[8];
    const float* gamma    = (const float*)d_in[9];
    float* out = (float*)d_out;

    // Workspace layout — total 135,266,304 B (proven footprint)
    char* ws = (char*)d_ws;
    float* se   = (float*)(ws + 8192);               //    8192 +     8 KB
    f16*   Ph   = (f16*)  (ws + 16384);              //   16384 +   256 KB
    f16*   wt   = (f16*)  (ws + 278528);             //  278528 +   576 KB
    f16*   xs   = (f16*)  (ws + 1048576);            // 1 MB    +    64 MB
    float* simp = (float*)(ws + 1048576);            // aliases xs (post-conv)
    f16*   yh   = (f16*)  (ws + 68157440);           //         +    32 MB
    float* avgp = (float*)(ws + 68157440);           // aliases yh (pre-conv), 1 MB
    f16*   yt   = (f16*)  (ws + 101711872);          //         +    32 MB

    prep_kernel<<<dim3(H_, B_), 256, 0, stream>>>(x1, x2, conv_w, avgp, xs, wt);
    se_mlp_kernel<<<dim3(B_), 256, 0, stream>>>(avgp, se_w1, se_w2, se);

    hipFuncSetAttribute((const void*)conv_mfma_big,
        hipFuncAttributeMaxDynamicSharedMemorySize, SMEM_BYTES);
    conv_mfma_big<<<dim3(H_ / 2, 2, B_), 512, SMEM_BYTES, stream>>>(
        xs, wt, se, bn_gamma, bn_beta, bn_mean, bn_var, yh, yt);

    sim_mfma_kernel<<<dim3(NS_, B_), 512, 0, stream>>>(yh, simp);
    softmax_kernel<<<dim3(B_ * C_), 128, 0, stream>>>(simp, Ph);
    feat_mfma_kernel<<<dim3(HW_ / 128, B_), 256, 0, stream>>>(Ph, yt, yh, gamma, out);
}